// Round 1
// baseline (1030.457 us; speedup 1.0000x reference)
//
#include <hip/hip_runtime.h>
#include <hip/hip_bf16.h>
#include <stdint.h>

// Problem constants (from reference): x:(4,4096,4096) f32, weight:(4096,4096) f32,
// bias:(4096,) f32, fixed_base:(32,) f32, fixed_sign_flag:(32,) f32.
// out:(4,4096,4096) f32.  M=16384, N=4096, K=4096. Group size 128 (both base & r quant).
#define H_DIM   4096
#define OUT_DIM 4096
#define M_TOTAL 16384
#define NGROUP  32      // groups per row (H/128)
#define GSZ     128

#define BM 128
#define BN 128
#define BK 64

typedef float  f32x4  __attribute__((ext_vector_type(4)));
typedef __bf16 bf16x8 __attribute__((ext_vector_type(8)));

// ---------------------------------------------------------------------------
// async global->LDS, 16B per lane. LDS dest is wave-uniform base + lane*16.
__device__ __forceinline__ void ld_g2l_16(const void* gptr, void* ldsptr) {
  __builtin_amdgcn_global_load_lds(
      (const __attribute__((address_space(1))) uint32_t*)gptr,
      (__attribute__((address_space(3))) uint32_t*)ldsptr,
      16 /*bytes*/, 0 /*offset*/, 0 /*aux*/);
}

// ---------------------------------------------------------------------------
// Pre-pass 1: quotient/remainder fake-quant of x -> bf16 x'.
// One wave handles one 128-element group (2 floats/lane).
__global__ void quant_x_kernel(const float* __restrict__ x,
                               const float* __restrict__ fixed_base,
                               const float* __restrict__ fixed_sign,
                               __hip_bfloat16* __restrict__ xq) {
  const int  wave = threadIdx.x >> 6;
  const int  lane = threadIdx.x & 63;
  const long gi   = (long)blockIdx.x * 4 + wave;   // global group index
  const int  g    = (int)(gi & (NGROUP - 1));      // group within row
  const long row  = gi >> 5;                       // row index
  const long off  = row * H_DIM + (long)g * GSZ + lane * 2;

  const float2 xv = *(const float2*)(x + off);
  const float  s  = fixed_sign[g];
  const float  b  = fixed_base[g];
  const float  hb = b * 0.5f;

  float q0 = (xv.x * s >= hb) ? 1.0f : 0.0f;
  float q1 = (xv.y * s >= hb) ? 1.0f : 0.0f;
  float r0 = xv.x - s * b * q0;
  float r1 = xv.y - s * b * q1;

  // group max |r| over the wave (128 elements)
  float m = fmaxf(fabsf(r0), fabsf(r1));
#pragma unroll
  for (int d = 32; d > 0; d >>= 1) m = fmaxf(m, __shfl_xor(m, d, 64));
  m = fmaxf(m, 1e-8f);

  const float scale = m / 7.0f;   // r_max = 2^(4-1)-1 = 7
  float t0 = fminf(fmaxf(rintf(r0 / scale), -8.0f), 7.0f);  // rintf = round-half-even, matches jnp.round
  float t1 = fminf(fmaxf(rintf(r1 / scale), -8.0f), 7.0f);

  const float sb = s * b;
  const float o0 = q0 * sb + t0 * scale;  // q_scaled + r_dq
  const float o1 = q1 * sb + t1 * scale;

  __hip_bfloat162 o;
  o.x = __float2bfloat16(o0);
  o.y = __float2bfloat16(o1);
  *(__hip_bfloat162*)(xq + off) = o;
}

// ---------------------------------------------------------------------------
// Pre-pass 2: weight f32 -> bf16.
__global__ void wconv_kernel(const float* __restrict__ w,
                             __hip_bfloat16* __restrict__ wq) {
  const size_t i = ((size_t)blockIdx.x * blockDim.x + threadIdx.x) * 4;
  const float4 v = *(const float4*)(w + i);
  __hip_bfloat162 p0, p1;
  p0.x = __float2bfloat16(v.x); p0.y = __float2bfloat16(v.y);
  p1.x = __float2bfloat16(v.z); p1.y = __float2bfloat16(v.w);
  *(__hip_bfloat162*)(wq + i)     = p0;
  *(__hip_bfloat162*)(wq + i + 2) = p1;
}

// ---------------------------------------------------------------------------
// GEMM: C[M,N] = A[M,K](bf16,row-major) * W[N,K](bf16,row-major)^T + bias.
// m97 structure: 128x128 tile, BK=64, 4 waves, 4x4 grid of 16x16x32 MFMA,
// global_load_lds width-16 staging, unpadded LDS, ds_read_b128 fragments.
__global__ void gemm_bt_kernel(const __hip_bfloat16* __restrict__ A,
                               const __hip_bfloat16* __restrict__ W,
                               const float* __restrict__ bias,
                               float* __restrict__ C) {
  __shared__ __bf16 As[BM * BK];   // 16 KB
  __shared__ __bf16 Bs[BN * BK];   // 16 KB

  const int tid  = threadIdx.x;
  const int wave = tid >> 6;
  const int lane = tid & 63;
  const int quad = lane >> 4;
  const int l15  = lane & 15;
  const int wm   = wave & 1;       // wave's 64-row block within tile
  const int wn   = wave >> 1;      // wave's 64-col block within tile

  const long rowBase = (long)blockIdx.y * BM;
  const long colBase = (long)blockIdx.x * BN;

  // staging coordinates (per-lane): each wave-round writes 8 rows x 64 cols
  const int sRow = lane >> 3;        // 0..7
  const int sCol = (lane & 7) * 8;   // bf16 col, 8 bf16 = 16B per lane

  f32x4 acc[4][4] = {};

  for (int kt = 0; kt < H_DIM; kt += BK) {
    __syncthreads();  // previous iteration's ds_reads complete before overwrite
#pragma unroll
    for (int r = 0; r < 4; ++r) {
      const int arow = r * 32 + wave * 8 + sRow;
      const __hip_bfloat16* ga = A + (rowBase + arow) * H_DIM + kt + sCol;
      ld_g2l_16(ga, (char*)As + (r * 4 + wave) * 1024);
      const __hip_bfloat16* gb = W + (colBase + arow) * H_DIM + kt + sCol;
      ld_g2l_16(gb, (char*)Bs + (r * 4 + wave) * 1024);
    }
    __builtin_amdgcn_s_waitcnt(0x0f70);  // vmcnt(0)
    __syncthreads();

#pragma unroll
    for (int ks = 0; ks < 2; ++ks) {
      const int kk = ks * 32 + quad * 8;
      bf16x8 af[4], bf[4];
#pragma unroll
      for (int i = 0; i < 4; ++i)
        af[i] = *(const bf16x8*)&As[(wm * 64 + i * 16 + l15) * BK + kk];
#pragma unroll
      for (int j = 0; j < 4; ++j)
        bf[j] = *(const bf16x8*)&Bs[(wn * 64 + j * 16 + l15) * BK + kk];
#pragma unroll
      for (int i = 0; i < 4; ++i)
#pragma unroll
        for (int j = 0; j < 4; ++j)
          acc[i][j] = __builtin_amdgcn_mfma_f32_16x16x32_bf16(af[i], bf[j], acc[i][j], 0, 0, 0);
    }
  }

  // epilogue: C/D layout col = lane&15, row = quad*4 + reg  (m89-verified)
#pragma unroll
  for (int i = 0; i < 4; ++i) {
#pragma unroll
    for (int j = 0; j < 4; ++j) {
      const long r0 = rowBase + wm * 64 + i * 16 + quad * 4;
      const long c  = colBase + wn * 64 + j * 16 + l15;
      const float bv = bias[c];
#pragma unroll
      for (int rg = 0; rg < 4; ++rg)
        C[(r0 + rg) * OUT_DIM + c] = acc[i][j][rg] + bv;
    }
  }
}

// ---------------------------------------------------------------------------
extern "C" void kernel_launch(void* const* d_in, const int* in_sizes, int n_in,
                              void* d_out, int out_size, void* d_ws, size_t ws_size,
                              hipStream_t stream) {
  const float* x          = (const float*)d_in[0];
  const float* weight     = (const float*)d_in[1];
  const float* bias       = (const float*)d_in[2];
  const float* fixed_base = (const float*)d_in[3];
  const float* fixed_sign = (const float*)d_in[4];
  float* out = (float*)d_out;

  // workspace: x' bf16 (128 MiB) + W bf16 (32 MiB) = 160 MiB
  __hip_bfloat16* xq = (__hip_bfloat16*)d_ws;
  __hip_bfloat16* wq = xq + (size_t)M_TOTAL * H_DIM;

  // pre-pass 1: 16384 rows * 32 groups, 4 groups per 256-thread block
  quant_x_kernel<<<(M_TOTAL * NGROUP) / 4, 256, 0, stream>>>(x, fixed_base, fixed_sign, xq);
  // pre-pass 2: 4096*4096 elems, 4 per thread
  wconv_kernel<<<(OUT_DIM * H_DIM) / (256 * 4), 256, 0, stream>>>(weight, wq);

  dim3 grid(OUT_DIM / BN, M_TOTAL / BM);
  gemm_bt_kernel<<<grid, 256, 0, stream>>>(xq, wq, bias, out);
}

// Round 2
// 944.427 us; speedup vs baseline: 1.0911x; 1.0911x over previous
//
#include <hip/hip_runtime.h>
#include <hip/hip_bf16.h>
#include <stdint.h>

// x:(4,4096,4096) f32, weight:(4096,4096) f32, bias:(4096,) f32,
// fixed_base:(32,) f32, fixed_sign_flag:(32,) f32 -> out:(4,4096,4096) f32.
// M=16384, N=4096, K=4096. Group size 128.
#define H_DIM   4096
#define OUT_DIM 4096
#define M_TOTAL 16384
#define NGROUP  32
#define GSZ     128

#define BM 128
#define BN 128
#define BK 64

typedef float  f32x4  __attribute__((ext_vector_type(4)));
typedef __bf16 bf16x8 __attribute__((ext_vector_type(8)));
typedef __bf16 bf16x4 __attribute__((ext_vector_type(4)));

// async global->LDS, 16B/lane. LDS dest = wave-uniform base + lane*16 (fixed);
// we control WHICH global chunk each lane fetches (that's where the swizzle goes).
__device__ __forceinline__ void ld_g2l_16(const void* gptr, void* ldsptr) {
  __builtin_amdgcn_global_load_lds(
      (const __attribute__((address_space(1))) uint32_t*)gptr,
      (__attribute__((address_space(3))) uint32_t*)ldsptr,
      16, 0, 0);
}

// ---------------------------------------------------------------------------
// Pre-pass 1: quotient/remainder fake-quant of x -> bf16 x'.
// 32 lanes per 128-elem group, 4 floats/lane (float4), 8 groups per 256-block.
__global__ void quant_x_kernel(const float* __restrict__ x,
                               const float* __restrict__ fixed_base,
                               const float* __restrict__ fixed_sign,
                               __hip_bfloat16* __restrict__ xq) {
  const int  tid = threadIdx.x;
  const long gi  = (long)blockIdx.x * 8 + (tid >> 5);  // global group index
  const int  lg  = tid & 31;                           // lane within group
  const int  g   = (int)(gi & (NGROUP - 1));
  const long row = gi >> 5;
  const long off = row * H_DIM + (long)g * GSZ + lg * 4;

  const float4 xv = *(const float4*)(x + off);
  const float  s  = fixed_sign[g];
  const float  b  = fixed_base[g];
  const float  hb = b * 0.5f;
  const float  sb = s * b;

  float q[4], r[4];
  const float xin[4] = {xv.x, xv.y, xv.z, xv.w};
#pragma unroll
  for (int k = 0; k < 4; ++k) {
    q[k] = (xin[k] * s >= hb) ? 1.0f : 0.0f;
    r[k] = xin[k] - sb * q[k];
  }

  float m = fmaxf(fmaxf(fabsf(r[0]), fabsf(r[1])), fmaxf(fabsf(r[2]), fabsf(r[3])));
#pragma unroll
  for (int d = 16; d > 0; d >>= 1) m = fmaxf(m, __shfl_xor(m, d, 64));  // masks <32 stay in the 32-lane group
  m = fmaxf(m, 1e-8f);

  const float scale = m / 7.0f;
  const float inv_s = 7.0f / m;
  bf16x4 o;
#pragma unroll
  for (int k = 0; k < 4; ++k) {
    float t = fminf(fmaxf(rintf(r[k] * inv_s), -8.0f), 7.0f);  // rintf = round-half-even = jnp.round
    o[k] = (__bf16)(q[k] * sb + t * scale);
  }
  *(bf16x4*)(xq + off) = o;
}

// ---------------------------------------------------------------------------
// Pre-pass 2: weight f32 -> bf16, 8 floats/thread.
__global__ void wconv_kernel(const float* __restrict__ w,
                             __hip_bfloat16* __restrict__ wq) {
  const size_t i = ((size_t)blockIdx.x * blockDim.x + threadIdx.x) * 8;
  const float4 v0 = *(const float4*)(w + i);
  const float4 v1 = *(const float4*)(w + i + 4);
  bf16x8 o;
  o[0] = (__bf16)v0.x; o[1] = (__bf16)v0.y; o[2] = (__bf16)v0.z; o[3] = (__bf16)v0.w;
  o[4] = (__bf16)v1.x; o[5] = (__bf16)v1.y; o[6] = (__bf16)v1.z; o[7] = (__bf16)v1.w;
  *(bf16x8*)(wq + i) = o;
}

// ---------------------------------------------------------------------------
// GEMM: C[M,N] = A[M,K] * W[N,K]^T + bias, bf16 in / f32 out.
// m97 structure + XOR-swizzled LDS: tile row r's 16B-chunk c is stored at
// LDS chunk (c ^ (r&7)). Staging applies the swizzle on the GLOBAL address
// (LDS side of global_load_lds is fixed); reads un-swizzle. This spreads each
// quad's 16 lanes over all 8 bank groups (2-way = free) instead of 16-on-4.
__global__ void gemm_bt_kernel(const __hip_bfloat16* __restrict__ A,
                               const __hip_bfloat16* __restrict__ W,
                               const float* __restrict__ bias,
                               float* __restrict__ C) {
  __shared__ __bf16 As[BM * BK];   // 16 KB
  __shared__ __bf16 Bs[BN * BK];   // 16 KB

  const int tid  = threadIdx.x;
  const int wave = tid >> 6;
  const int lane = tid & 63;
  const int quad = lane >> 4;
  const int l15  = lane & 15;
  const int sw   = l15 & 7;        // read-side swizzle key = row&7
  const int wm   = wave & 1;
  const int wn   = wave >> 1;

  const long rowBase = (long)blockIdx.y * BM;
  const long colBase = (long)blockIdx.x * BN;

  // staging: lane's LDS slot = (sRow, chunk sChunk); it must carry global
  // chunk (sChunk ^ sRow)  [arow&7 == sRow since wave-round base is 8-aligned]
  const int sRow  = lane >> 3;
  const int sCol  = ((lane & 7) ^ sRow) * 8;   // swizzled global bf16 col

  f32x4 acc[4][4] = {};

  for (int kt = 0; kt < H_DIM; kt += BK) {
    __syncthreads();
#pragma unroll
    for (int r = 0; r < 4; ++r) {
      const int arow = r * 32 + wave * 8 + sRow;
      ld_g2l_16(A + (rowBase + arow) * H_DIM + kt + sCol,
                (char*)As + (r * 4 + wave) * 1024);
      ld_g2l_16(W + (colBase + arow) * H_DIM + kt + sCol,
                (char*)Bs + (r * 4 + wave) * 1024);
    }
    __builtin_amdgcn_s_waitcnt(0x0f70);  // vmcnt(0)
    __syncthreads();

#pragma unroll
    for (int ks = 0; ks < 2; ++ks) {
      bf16x8 af[4], bf[4];
      const int ck = ((ks * 4 + quad) ^ sw) * 8;   // un-swizzled LDS chunk -> bf16 offset
#pragma unroll
      for (int i = 0; i < 4; ++i)
        af[i] = *(const bf16x8*)&As[(wm * 64 + i * 16 + l15) * BK + ck];
#pragma unroll
      for (int j = 0; j < 4; ++j)
        bf[j] = *(const bf16x8*)&Bs[(wn * 64 + j * 16 + l15) * BK + ck];
#pragma unroll
      for (int i = 0; i < 4; ++i)
#pragma unroll
        for (int j = 0; j < 4; ++j)
          acc[i][j] = __builtin_amdgcn_mfma_f32_16x16x32_bf16(af[i], bf[j], acc[i][j], 0, 0, 0);
    }
  }

  // epilogue: C/D layout col = lane&15, row = quad*4 + reg (m89-verified)
#pragma unroll
  for (int i = 0; i < 4; ++i) {
#pragma unroll
    for (int j = 0; j < 4; ++j) {
      const long r0 = rowBase + wm * 64 + i * 16 + quad * 4;
      const long c  = colBase + wn * 64 + j * 16 + l15;
      const float bv = bias[c];
#pragma unroll
      for (int rg = 0; rg < 4; ++rg)
        C[(r0 + rg) * OUT_DIM + c] = acc[i][j][rg] + bv;
    }
  }
}

// ---------------------------------------------------------------------------
extern "C" void kernel_launch(void* const* d_in, const int* in_sizes, int n_in,
                              void* d_out, int out_size, void* d_ws, size_t ws_size,
                              hipStream_t stream) {
  const float* x          = (const float*)d_in[0];
  const float* weight     = (const float*)d_in[1];
  const float* bias       = (const float*)d_in[2];
  const float* fixed_base = (const float*)d_in[3];
  const float* fixed_sign = (const float*)d_in[4];
  float* out = (float*)d_out;

  __hip_bfloat16* xq = (__hip_bfloat16*)d_ws;                  // 128 MiB
  __hip_bfloat16* wq = xq + (size_t)M_TOTAL * H_DIM;           // +32 MiB

  quant_x_kernel<<<(M_TOTAL * NGROUP) / 8, 256, 0, stream>>>(x, fixed_base, fixed_sign, xq);
  wconv_kernel<<<(OUT_DIM * H_DIM) / (256 * 8), 256, 0, stream>>>(weight, wq);

  dim3 grid(OUT_DIM / BN, M_TOTAL / BM);
  gemm_bt_kernel<<<grid, 256, 0, stream>>>(xq, wq, bias, out);
}